// Round 1
// 2483.348 us; speedup vs baseline: 1.8857x; 1.8857x over previous
//
#include <hip/hip_runtime.h>
#include <math.h>

// LPCDARTS forward on MI355X — v5: MFMA fp16 conv.
// conv_edge is an implicit GEMM on matrix cores: per edge, C[64o][n*1024px]
// += sum_tap W[o][c][tap] * X[c][px+shift].  fp16 inputs, fp32 accumulate.
// Identity (w[0]) kept in fp32 in the epilogue for accuracy.

#define NB 64
#define CF 256
#define PC 64
#define HW 32
#define NEDGE 10
#define TAPS 81

// LDS tile geometry: 16 staged rows (8 output + 2*4 halo) x 40 cols x 32 ch
#define TR 16
#define TC 40
#define CSTR 40            // halves per pixel (32 ch + 8 pad) = 80 B
#define ROWSTR (TC * CSTR) // 1600 halves per row

typedef _Float16 f16x8 __attribute__((ext_vector_type(8)));
typedef _Float16 f16x2 __attribute__((ext_vector_type(2)));
typedef float f32x4 __attribute__((ext_vector_type(4)));

// ---------------- softmax over arch params (10 edges x 12 ops) -------------
__global__ void softmax_kernel(const float* __restrict__ arch,
                               const float* __restrict__ norms,
                               float* __restrict__ sw) {
    int e = threadIdx.x;
    if (e >= NEDGE) return;
    int node = 0, i = e;
    while (i > node) { i -= node + 1; node++; }
    float norm = fmaxf(norms[node * 5 + i], 1e-5f);
    const float* a = arch + (node * 5 + i) * 12;
    float v[12];
    float m = -3.0e38f;
    for (int k = 0; k < 12; ++k) { v[k] = a[k] / norm; m = fmaxf(m, v[k]); }
    float ssum = 0.f;
    for (int k = 0; k < 12; ++k) { v[k] = expf(v[k] - m); ssum += v[k]; }
    float inv = 1.0f / ssum;
    for (int k = 0; k < 12; ++k) sw[e * 12 + k] = v[k] * inv;
}

// ---------------- build combined 9x9 fp16 weights --------------------------
// Layout: Wh[e][tap][g][o][c32] halves (g = c>>5).  NO identity term (fp32
// epilogue handles w[0]).  gid is linear in the OUTPUT layout so the 2B
// stores are coalesced.
__global__ void build_w(const float* __restrict__ w3, const float* __restrict__ w5,
                        const float* __restrict__ w7, const float* __restrict__ w1,
                        const float* __restrict__ s3dw, const float* __restrict__ s3pw,
                        const float* __restrict__ s5dw, const float* __restrict__ s5pw,
                        const float* __restrict__ d3, const float* __restrict__ d5,
                        const float* __restrict__ sw, _Float16* __restrict__ Wh) {
    int gid = blockIdx.x * 256 + threadIdx.x;  // 10*81*2*64*32 = 3,317,760
    int c32 = gid & 31;
    int o   = (gid >> 5) & 63;
    int g   = (gid >> 11) & 1;
    int t2  = gid >> 12;          // e*81 + tap
    int tap = t2 % TAPS;
    int e   = t2 / TAPS;
    int c   = (g << 5) | c32;

    int dy = tap / 9 - 4, dx = tap % 9 - 4;
    const float* w = sw + e * 12;
    int eoc = (e * 64 + o) * 64 + c;
    int ec  = e * 64 + c;
    float val = 0.f;
    int ady = dy < 0 ? -dy : dy, adx = dx < 0 ? -dx : dx;
    if (ady <= 1 && adx <= 1) {
        val += w[1] * w3[eoc * 9 + (dy + 1) * 3 + (dx + 1)];
        val += w[7] * s3pw[eoc] * s3dw[ec * 9 + (dy + 1) * 3 + (dx + 1)];
    }
    if (ady <= 2 && adx <= 2) {
        val += w[2] * w5[eoc * 25 + (dy + 2) * 5 + (dx + 2)];
        val += w[8] * s5pw[eoc] * s5dw[ec * 25 + (dy + 2) * 5 + (dx + 2)];
        if (((dy | dx) & 1) == 0)
            val += w[9] * d3[eoc * 9 + (dy / 2 + 1) * 3 + (dx / 2 + 1)];
    }
    if (ady <= 3 && adx <= 3)
        val += w[3] * w7[eoc * 49 + (dy + 3) * 7 + (dx + 3)];
    if (((dy | dx) & 1) == 0)
        val += w[10] * d5[eoc * 25 + (dy / 2 + 2) * 5 + (dx / 2 + 2)];
    if (dy == 0 && dx == 0)
        val += w[4] * w1[eoc];     // identity w[0] deliberately NOT added
    Wh[gid] = (_Float16)val;
}

// ---------------- pools (also zero-inits acc) ------------------------------
__global__ void pool_node(const float* __restrict__ s0, const float* __restrict__ s1,
                          const float* __restrict__ s2, const float* __restrict__ s3,
                          float* __restrict__ acc, const float* __restrict__ sw,
                          int ebase, int nedges) {
    int gid = blockIdx.x * 256 + threadIdx.x;  // over 64*256*1024
    int x = gid & 31;
    int y = (gid >> 5) & 31;
    int plane = gid >> 10;
    const float* states[4] = {s0, s1, s2, s3};
    float val = 0.f;
    for (int i = 0; i < nedges; ++i) {
        const float* base = states[i] + (plane << 10);
        float mx = -3.0e38f;
        float sum = 0.f;
        #pragma unroll
        for (int dy = -1; dy <= 1; ++dy) {
            #pragma unroll
            for (int dx = -1; dx <= 1; ++dx) {
                int yy = y + dy, xx = x + dx;
                if ((unsigned)yy < 32u && (unsigned)xx < 32u) {
                    float v = base[yy * 32 + xx];
                    mx = fmaxf(mx, v);
                    sum += v;
                }
            }
        }
        val += sw[(ebase + i) * 12 + 5] * mx + sw[(ebase + i) * 12 + 6] * (sum * (1.0f / 9.0f));
    }
    acc[gid] = val;
}

// ---------------- MFMA conv for one edge -----------------------------------
// Block: 256 thr (4 waves), tile = (n, 8 image rows), all 64 o, all 32 px/row.
// Wave w owns rows y0+2w, y0+2w+1 (64 px) x 64 o = 16 C-frags (16x16x32 f16).
// Grid: 64 n x 4 row-strips = 256 blocks.
__global__ __launch_bounds__(256, 2) void conv_edge(
    const float* __restrict__ s, float* __restrict__ acc,
    const _Float16* __restrict__ Wh, const int* __restrict__ idxg,
    const float* __restrict__ sw, int e) {
    __shared__ __align__(16) _Float16 tile[TR * ROWSTR];  // 51,200 B

    int t  = threadIdx.x;
    int qy = blockIdx.x & 3;
    int n  = blockIdx.x >> 2;
    int y0 = qy << 3;

    // zero the tile once: halo cols/rows stay zero through both groups
    for (int i = t; i < TR * ROWSTR / 8; i += 256)
        ((f32x4*)tile)[i] = (f32x4){0.f, 0.f, 0.f, 0.f};

    int lane = t & 63;
    int wave = __builtin_amdgcn_readfirstlane(t >> 6);
    int aoff = ((lane & 15) << 5) + ((lane >> 4) << 3);   // halves into [o][c] 2048-chunk
    int boff = (lane & 15) * CSTR + ((lane >> 4) << 3);   // halves into tile row

    int sx = t & 31;        // staging x
    int cp = t >> 5;        // staging channel-pair slot 0..7

    f32x4 a[4][4];          // [o-frag][rowsel*2+colblk]
    #pragma unroll
    for (int i = 0; i < 4; ++i)
        #pragma unroll
        for (int p = 0; p < 4; ++p) a[i][p] = (f32x4){0.f, 0.f, 0.f, 0.f};

    const int* ide = idxg + e * PC;

    __syncthreads();

    for (int g = 0; g < 2; ++g) {
        // ---- stage 32 gathered channels fp32->fp16 into [row][px][c] ----
        #pragma unroll
        for (int sub = 0; sub < 2; ++sub) {
            int c2 = cp + (sub << 3);                  // 0..15
            int ca = (g << 5) + (c2 << 1);
            const float* pa = s + (((size_t)n * CF + ide[ca]) << 10);
            const float* pb = s + (((size_t)n * CF + ide[ca + 1]) << 10);
            #pragma unroll
            for (int r = 0; r < TR; ++r) {
                int ys = y0 - 4 + r;
                if ((unsigned)ys < 32u) {
                    f16x2 h = {(_Float16)pa[(ys << 5) + sx], (_Float16)pb[(ys << 5) + sx]};
                    *(f16x2*)&tile[r * ROWSTR + (4 + sx) * CSTR + (c2 << 1)] = h;
                }
            }
        }
        __syncthreads();

        const _Float16* wg = Wh + ((size_t)(e * TAPS) * 2 + g) * 2048 + aoff;
        for (int dy = 0; dy < 9; ++dy) {
            const _Float16* t0  = tile + ((wave << 1) + dy) * ROWSTR + boff;
            const _Float16* wdy = wg + dy * 9 * 4096;
            #pragma unroll
            for (int dx = 0; dx < 9; ++dx) {
                const _Float16* wp = wdy + dx * 4096;
                f16x8 A0 = *(const f16x8*)(wp);
                f16x8 A1 = *(const f16x8*)(wp + 512);
                f16x8 A2 = *(const f16x8*)(wp + 1024);
                f16x8 A3 = *(const f16x8*)(wp + 1536);
                const _Float16* bp = t0 + dx * CSTR;
                f16x8 B00 = *(const f16x8*)(bp);
                f16x8 B01 = *(const f16x8*)(bp + 16 * CSTR);
                f16x8 B10 = *(const f16x8*)(bp + ROWSTR);
                f16x8 B11 = *(const f16x8*)(bp + ROWSTR + 16 * CSTR);
                a[0][0] = __builtin_amdgcn_mfma_f32_16x16x32_f16(A0, B00, a[0][0], 0, 0, 0);
                a[0][1] = __builtin_amdgcn_mfma_f32_16x16x32_f16(A0, B01, a[0][1], 0, 0, 0);
                a[0][2] = __builtin_amdgcn_mfma_f32_16x16x32_f16(A0, B10, a[0][2], 0, 0, 0);
                a[0][3] = __builtin_amdgcn_mfma_f32_16x16x32_f16(A0, B11, a[0][3], 0, 0, 0);
                a[1][0] = __builtin_amdgcn_mfma_f32_16x16x32_f16(A1, B00, a[1][0], 0, 0, 0);
                a[1][1] = __builtin_amdgcn_mfma_f32_16x16x32_f16(A1, B01, a[1][1], 0, 0, 0);
                a[1][2] = __builtin_amdgcn_mfma_f32_16x16x32_f16(A1, B10, a[1][2], 0, 0, 0);
                a[1][3] = __builtin_amdgcn_mfma_f32_16x16x32_f16(A1, B11, a[1][3], 0, 0, 0);
                a[2][0] = __builtin_amdgcn_mfma_f32_16x16x32_f16(A2, B00, a[2][0], 0, 0, 0);
                a[2][1] = __builtin_amdgcn_mfma_f32_16x16x32_f16(A2, B01, a[2][1], 0, 0, 0);
                a[2][2] = __builtin_amdgcn_mfma_f32_16x16x32_f16(A2, B10, a[2][2], 0, 0, 0);
                a[2][3] = __builtin_amdgcn_mfma_f32_16x16x32_f16(A2, B11, a[2][3], 0, 0, 0);
                a[3][0] = __builtin_amdgcn_mfma_f32_16x16x32_f16(A3, B00, a[3][0], 0, 0, 0);
                a[3][1] = __builtin_amdgcn_mfma_f32_16x16x32_f16(A3, B01, a[3][1], 0, 0, 0);
                a[3][2] = __builtin_amdgcn_mfma_f32_16x16x32_f16(A3, B10, a[3][2], 0, 0, 0);
                a[3][3] = __builtin_amdgcn_mfma_f32_16x16x32_f16(A3, B11, a[3][3], 0, 0, 0);
            }
        }
        if (g == 0) __syncthreads();   // protect tile before group-1 restage
    }

    // ---- epilogue: fp32 RMW into acc + fp32 identity term -----------------
    // C/D layout: col = lane&15 (px), row = (lane>>4)*4 + reg (o within frag)
    float w0 = sw[e * 12];
    #pragma unroll
    for (int of = 0; of < 4; ++of) {
        #pragma unroll
        for (int j = 0; j < 4; ++j) {
            int o = (of << 4) + ((lane >> 4) << 2) + j;
            int ch = ide[o];
            size_t base = ((size_t)n * CF + ch) << 10;
            float* ap = acc + base;
            const float* sp = s + base;
            #pragma unroll
            for (int rs = 0; rs < 2; ++rs) {
                int y = y0 + (wave << 1) + rs;
                #pragma unroll
                for (int cb = 0; cb < 2; ++cb) {
                    int off = (y << 5) + (cb << 4) + (lane & 15);
                    ap[off] += a[of][(rs << 1) + cb][j] + w0 * sp[off];
                }
            }
        }
    }
}

extern "C" void kernel_launch(void* const* d_in, const int* in_sizes, int n_in,
                              void* d_out, int out_size, void* d_ws, size_t ws_size,
                              hipStream_t stream) {
    const float* x    = (const float*)d_in[0];
    const float* arch = (const float*)d_in[1];
    const float* norms= (const float*)d_in[2];
    const int*   idx  = (const int*)d_in[3];
    const float* w3   = (const float*)d_in[4];
    const float* w5   = (const float*)d_in[5];
    const float* w7   = (const float*)d_in[6];
    const float* w1   = (const float*)d_in[7];
    const float* s3dw = (const float*)d_in[8];
    const float* s3pw = (const float*)d_in[9];
    const float* s5dw = (const float*)d_in[10];
    const float* s5pw = (const float*)d_in[11];
    const float* d3   = (const float*)d_in[12];
    const float* d5   = (const float*)d_in[13];
    float* out = (float*)d_out;

    const size_t S = (size_t)NB * CF * HW * HW;  // 16,777,216 floats
    float* st1 = (float*)d_ws;
    float* st2 = st1 + S;
    float* st3 = st2 + S;
    _Float16* Wh = (_Float16*)(st3 + S);         // 10*81*2*64*32 halves = 6.64 MB
    float* sw = (float*)(Wh + (size_t)NEDGE * TAPS * 2 * 2048);

    softmax_kernel<<<1, 64, 0, stream>>>(arch, norms, sw);
    build_w<<<(NEDGE * TAPS * 2 * 2048) / 256, 256, 0, stream>>>(
        w3, w5, w7, w1, s3dw, s3pw, s5dw, s5pw, d3, d5, sw, Wh);

    float* states[5] = {(float*)x, st1, st2, st3, out};
    int e = 0;
    for (int node = 0; node < 4; ++node) {
        int ebase = node * (node + 1) / 2;
        pool_node<<<(int)(S / 256), 256, 0, stream>>>(
            states[0], states[1], states[2], states[3],
            states[node + 1], sw, ebase, node + 1);
        for (int i = 0; i <= node; ++i) {
            conv_edge<<<NB * 4, 256, 0, stream>>>(states[i], states[node + 1], Wh, idx, sw, e);
            ++e;
        }
    }
}

// Round 3
// 1913.770 us; speedup vs baseline: 2.4469x; 1.2976x over previous
//
#include <hip/hip_runtime.h>
#include <math.h>

// LPCDARTS forward on MI355X — v6: MFMA fp16 conv + vectorized separable pools.
// conv_edge is an implicit GEMM on matrix cores: per edge, C[64o][n*1024px]
// += sum_tap W[o][c][tap] * X[c][px+shift].  fp16 inputs, fp32 accumulate.
// Identity (w[0]) kept in fp32 in the epilogue for accuracy.
// pool_node v6: 8 outputs/thread, float4 loads, separable col-max/col-sum.
// (Resubmission of round-1 kernel — round-2 bench failed with
//  GPUAcquisitionTimeout before any measurement.)

#define NB 64
#define CF 256
#define PC 64
#define HW 32
#define NEDGE 10
#define TAPS 81

// LDS tile geometry: 16 staged rows (8 output + 2*4 halo) x 40 cols x 32 ch
#define TR 16
#define TC 40
#define CSTR 40            // halves per pixel (32 ch + 8 pad) = 80 B
#define ROWSTR (TC * CSTR) // 1600 halves per row

typedef _Float16 f16x8 __attribute__((ext_vector_type(8)));
typedef _Float16 f16x2 __attribute__((ext_vector_type(2)));
typedef float f32x4 __attribute__((ext_vector_type(4)));

// ---------------- softmax over arch params (10 edges x 12 ops) -------------
__global__ void softmax_kernel(const float* __restrict__ arch,
                               const float* __restrict__ norms,
                               float* __restrict__ sw) {
    int e = threadIdx.x;
    if (e >= NEDGE) return;
    int node = 0, i = e;
    while (i > node) { i -= node + 1; node++; }
    float norm = fmaxf(norms[node * 5 + i], 1e-5f);
    const float* a = arch + (node * 5 + i) * 12;
    float v[12];
    float m = -3.0e38f;
    for (int k = 0; k < 12; ++k) { v[k] = a[k] / norm; m = fmaxf(m, v[k]); }
    float ssum = 0.f;
    for (int k = 0; k < 12; ++k) { v[k] = expf(v[k] - m); ssum += v[k]; }
    float inv = 1.0f / ssum;
    for (int k = 0; k < 12; ++k) sw[e * 12 + k] = v[k] * inv;
}

// ---------------- build combined 9x9 fp16 weights --------------------------
// Layout: Wh[e][tap][g][o][c32] halves (g = c>>5).  NO identity term (fp32
// epilogue handles w[0]).  gid is linear in the OUTPUT layout so the 2B
// stores are coalesced.
__global__ void build_w(const float* __restrict__ w3, const float* __restrict__ w5,
                        const float* __restrict__ w7, const float* __restrict__ w1,
                        const float* __restrict__ s3dw, const float* __restrict__ s3pw,
                        const float* __restrict__ s5dw, const float* __restrict__ s5pw,
                        const float* __restrict__ d3, const float* __restrict__ d5,
                        const float* __restrict__ sw, _Float16* __restrict__ Wh) {
    int gid = blockIdx.x * 256 + threadIdx.x;  // 10*81*2*64*32 = 3,317,760
    int c32 = gid & 31;
    int o   = (gid >> 5) & 63;
    int g   = (gid >> 11) & 1;
    int t2  = gid >> 12;          // e*81 + tap
    int tap = t2 % TAPS;
    int e   = t2 / TAPS;
    int c   = (g << 5) | c32;

    int dy = tap / 9 - 4, dx = tap % 9 - 4;
    const float* w = sw + e * 12;
    int eoc = (e * 64 + o) * 64 + c;
    int ec  = e * 64 + c;
    float val = 0.f;
    int ady = dy < 0 ? -dy : dy, adx = dx < 0 ? -dx : dx;
    if (ady <= 1 && adx <= 1) {
        val += w[1] * w3[eoc * 9 + (dy + 1) * 3 + (dx + 1)];
        val += w[7] * s3pw[eoc] * s3dw[ec * 9 + (dy + 1) * 3 + (dx + 1)];
    }
    if (ady <= 2 && adx <= 2) {
        val += w[2] * w5[eoc * 25 + (dy + 2) * 5 + (dx + 2)];
        val += w[8] * s5pw[eoc] * s5dw[ec * 25 + (dy + 2) * 5 + (dx + 2)];
        if (((dy | dx) & 1) == 0)
            val += w[9] * d3[eoc * 9 + (dy / 2 + 1) * 3 + (dx / 2 + 1)];
    }
    if (ady <= 3 && adx <= 3)
        val += w[3] * w7[eoc * 49 + (dy + 3) * 7 + (dx + 3)];
    if (((dy | dx) & 1) == 0)
        val += w[10] * d5[eoc * 25 + (dy / 2 + 2) * 5 + (dx / 2 + 2)];
    if (dy == 0 && dx == 0)
        val += w[4] * w1[eoc];     // identity w[0] deliberately NOT added
    Wh[gid] = (_Float16)val;
}

// ---------------- pools (also zero-inits acc) ------------------------------
// v6: thread computes 8 consecutive x outputs of one row.  Per edge per row:
// 2 aligned float4 loads + 2 border scalars; separable col-max/col-sum
// (3 rows) then 3-tap horizontal reduce.  S/8 threads total.
__global__ void pool_node(const float* __restrict__ s0, const float* __restrict__ s1,
                          const float* __restrict__ s2, const float* __restrict__ s3,
                          float* __restrict__ acc, const float* __restrict__ sw,
                          int ebase, int nedges) {
    int gid = blockIdx.x * 256 + threadIdx.x;  // over S/8 = 2,097,152
    int x0 = (gid & 3) << 3;                   // 0,8,16,24
    int y  = (gid >> 2) & 31;
    size_t plane = (size_t)(gid >> 7);         // (n, c)
    const float* states[4] = {s0, s1, s2, s3};
    float outv[8];
    #pragma unroll
    for (int j = 0; j < 8; ++j) outv[j] = 0.f;

    for (int i = 0; i < nedges; ++i) {
        const float* base = states[i] + (plane << 10);
        float colmax[10], colsum[10];
        #pragma unroll
        for (int j = 0; j < 10; ++j) { colmax[j] = -3.0e38f; colsum[j] = 0.f; }
        #pragma unroll
        for (int dr = -1; dr <= 1; ++dr) {
            int r = y + dr;
            if ((unsigned)r < 32u) {
                const float* rp = base + (r << 5);
                float vals[10];
                vals[0] = (x0 > 0) ? rp[x0 - 1] : 0.f;
                f32x4 m0 = *(const f32x4*)(rp + x0);
                f32x4 m1 = *(const f32x4*)(rp + x0 + 4);
                vals[1] = m0.x; vals[2] = m0.y; vals[3] = m0.z; vals[4] = m0.w;
                vals[5] = m1.x; vals[6] = m1.y; vals[7] = m1.z; vals[8] = m1.w;
                vals[9] = (x0 < 24) ? rp[x0 + 8] : 0.f;
                #pragma unroll
                for (int j = 0; j < 10; ++j) {
                    colsum[j] += vals[j];
                    colmax[j] = fmaxf(colmax[j], vals[j]);
                }
            }
        }
        // border columns: sum contribution 0 is correct; max must be -inf
        if (x0 == 0)  colmax[0] = -3.0e38f;
        if (x0 == 24) colmax[9] = -3.0e38f;

        float wmax = sw[(ebase + i) * 12 + 5];
        float wavg = sw[(ebase + i) * 12 + 6] * (1.0f / 9.0f);
        #pragma unroll
        for (int j = 0; j < 8; ++j) {
            float mx = fmaxf(fmaxf(colmax[j], colmax[j + 1]), colmax[j + 2]);
            float sm = colsum[j] + colsum[j + 1] + colsum[j + 2];
            outv[j] += wmax * mx + wavg * sm;
        }
    }
    float* op = acc + (plane << 10) + (y << 5) + x0;
    ((f32x4*)op)[0] = (f32x4){outv[0], outv[1], outv[2], outv[3]};
    ((f32x4*)op)[1] = (f32x4){outv[4], outv[5], outv[6], outv[7]};
}

// ---------------- MFMA conv for one edge -----------------------------------
// Block: 256 thr (4 waves), tile = (n, 8 image rows), all 64 o, all 32 px/row.
// Wave w owns rows y0+2w, y0+2w+1 (64 px) x 64 o = 16 C-frags (16x16x32 f16).
// Grid: 64 n x 4 row-strips = 256 blocks.
__global__ __launch_bounds__(256, 2) void conv_edge(
    const float* __restrict__ s, float* __restrict__ acc,
    const _Float16* __restrict__ Wh, const int* __restrict__ idxg,
    const float* __restrict__ sw, int e) {
    __shared__ __align__(16) _Float16 tile[TR * ROWSTR];  // 51,200 B

    int t  = threadIdx.x;
    int qy = blockIdx.x & 3;
    int n  = blockIdx.x >> 2;
    int y0 = qy << 3;

    // zero the tile once: halo cols/rows stay zero through both groups
    for (int i = t; i < TR * ROWSTR / 8; i += 256)
        ((f32x4*)tile)[i] = (f32x4){0.f, 0.f, 0.f, 0.f};

    int lane = t & 63;
    int wave = __builtin_amdgcn_readfirstlane(t >> 6);
    int aoff = ((lane & 15) << 5) + ((lane >> 4) << 3);   // halves into [o][c] 2048-chunk
    int boff = (lane & 15) * CSTR + ((lane >> 4) << 3);   // halves into tile row

    int sx = t & 31;        // staging x
    int cp = t >> 5;        // staging channel-pair slot 0..7

    f32x4 a[4][4];          // [o-frag][rowsel*2+colblk]
    #pragma unroll
    for (int i = 0; i < 4; ++i)
        #pragma unroll
        for (int p = 0; p < 4; ++p) a[i][p] = (f32x4){0.f, 0.f, 0.f, 0.f};

    const int* ide = idxg + e * PC;

    __syncthreads();

    for (int g = 0; g < 2; ++g) {
        // ---- stage 32 gathered channels fp32->fp16 into [row][px][c] ----
        #pragma unroll
        for (int sub = 0; sub < 2; ++sub) {
            int c2 = cp + (sub << 3);                  // 0..15
            int ca = (g << 5) + (c2 << 1);
            const float* pa = s + (((size_t)n * CF + ide[ca]) << 10);
            const float* pb = s + (((size_t)n * CF + ide[ca + 1]) << 10);
            #pragma unroll
            for (int r = 0; r < TR; ++r) {
                int ys = y0 - 4 + r;
                if ((unsigned)ys < 32u) {
                    f16x2 h = {(_Float16)pa[(ys << 5) + sx], (_Float16)pb[(ys << 5) + sx]};
                    *(f16x2*)&tile[r * ROWSTR + (4 + sx) * CSTR + (c2 << 1)] = h;
                }
            }
        }
        __syncthreads();

        const _Float16* wg = Wh + ((size_t)(e * TAPS) * 2 + g) * 2048 + aoff;
        for (int dy = 0; dy < 9; ++dy) {
            const _Float16* t0  = tile + ((wave << 1) + dy) * ROWSTR + boff;
            const _Float16* wdy = wg + dy * 9 * 4096;
            #pragma unroll
            for (int dx = 0; dx < 9; ++dx) {
                const _Float16* wp = wdy + dx * 4096;
                f16x8 A0 = *(const f16x8*)(wp);
                f16x8 A1 = *(const f16x8*)(wp + 512);
                f16x8 A2 = *(const f16x8*)(wp + 1024);
                f16x8 A3 = *(const f16x8*)(wp + 1536);
                const _Float16* bp = t0 + dx * CSTR;
                f16x8 B00 = *(const f16x8*)(bp);
                f16x8 B01 = *(const f16x8*)(bp + 16 * CSTR);
                f16x8 B10 = *(const f16x8*)(bp + ROWSTR);
                f16x8 B11 = *(const f16x8*)(bp + ROWSTR + 16 * CSTR);
                a[0][0] = __builtin_amdgcn_mfma_f32_16x16x32_f16(A0, B00, a[0][0], 0, 0, 0);
                a[0][1] = __builtin_amdgcn_mfma_f32_16x16x32_f16(A0, B01, a[0][1], 0, 0, 0);
                a[0][2] = __builtin_amdgcn_mfma_f32_16x16x32_f16(A0, B10, a[0][2], 0, 0, 0);
                a[0][3] = __builtin_amdgcn_mfma_f32_16x16x32_f16(A0, B11, a[0][3], 0, 0, 0);
                a[1][0] = __builtin_amdgcn_mfma_f32_16x16x32_f16(A1, B00, a[1][0], 0, 0, 0);
                a[1][1] = __builtin_amdgcn_mfma_f32_16x16x32_f16(A1, B01, a[1][1], 0, 0, 0);
                a[1][2] = __builtin_amdgcn_mfma_f32_16x16x32_f16(A1, B10, a[1][2], 0, 0, 0);
                a[1][3] = __builtin_amdgcn_mfma_f32_16x16x32_f16(A1, B11, a[1][3], 0, 0, 0);
                a[2][0] = __builtin_amdgcn_mfma_f32_16x16x32_f16(A2, B00, a[2][0], 0, 0, 0);
                a[2][1] = __builtin_amdgcn_mfma_f32_16x16x32_f16(A2, B01, a[2][1], 0, 0, 0);
                a[2][2] = __builtin_amdgcn_mfma_f32_16x16x32_f16(A2, B10, a[2][2], 0, 0, 0);
                a[2][3] = __builtin_amdgcn_mfma_f32_16x16x32_f16(A2, B11, a[2][3], 0, 0, 0);
                a[3][0] = __builtin_amdgcn_mfma_f32_16x16x32_f16(A3, B00, a[3][0], 0, 0, 0);
                a[3][1] = __builtin_amdgcn_mfma_f32_16x16x32_f16(A3, B01, a[3][1], 0, 0, 0);
                a[3][2] = __builtin_amdgcn_mfma_f32_16x16x32_f16(A3, B10, a[3][2], 0, 0, 0);
                a[3][3] = __builtin_amdgcn_mfma_f32_16x16x32_f16(A3, B11, a[3][3], 0, 0, 0);
            }
        }
        if (g == 0) __syncthreads();   // protect tile before group-1 restage
    }

    // ---- epilogue: fp32 RMW into acc + fp32 identity term -----------------
    // C/D layout: col = lane&15 (px), row = (lane>>4)*4 + reg (o within frag)
    float w0 = sw[e * 12];
    #pragma unroll
    for (int of = 0; of < 4; ++of) {
        #pragma unroll
        for (int j = 0; j < 4; ++j) {
            int o = (of << 4) + ((lane >> 4) << 2) + j;
            int ch = ide[o];
            size_t base = ((size_t)n * CF + ch) << 10;
            float* ap = acc + base;
            const float* sp = s + base;
            #pragma unroll
            for (int rs = 0; rs < 2; ++rs) {
                int y = y0 + (wave << 1) + rs;
                #pragma unroll
                for (int cb = 0; cb < 2; ++cb) {
                    int off = (y << 5) + (cb << 4) + (lane & 15);
                    ap[off] += a[of][(rs << 1) + cb][j] + w0 * sp[off];
                }
            }
        }
    }
}

extern "C" void kernel_launch(void* const* d_in, const int* in_sizes, int n_in,
                              void* d_out, int out_size, void* d_ws, size_t ws_size,
                              hipStream_t stream) {
    const float* x    = (const float*)d_in[0];
    const float* arch = (const float*)d_in[1];
    const float* norms= (const float*)d_in[2];
    const int*   idx  = (const int*)d_in[3];
    const float* w3   = (const float*)d_in[4];
    const float* w5   = (const float*)d_in[5];
    const float* w7   = (const float*)d_in[6];
    const float* w1   = (const float*)d_in[7];
    const float* s3dw = (const float*)d_in[8];
    const float* s3pw = (const float*)d_in[9];
    const float* s5dw = (const float*)d_in[10];
    const float* s5pw = (const float*)d_in[11];
    const float* d3   = (const float*)d_in[12];
    const float* d5   = (const float*)d_in[13];
    float* out = (float*)d_out;

    const size_t S = (size_t)NB * CF * HW * HW;  // 16,777,216 floats
    float* st1 = (float*)d_ws;
    float* st2 = st1 + S;
    float* st3 = st2 + S;
    _Float16* Wh = (_Float16*)(st3 + S);         // 10*81*2*64*32 halves = 6.64 MB
    float* sw = (float*)(Wh + (size_t)NEDGE * TAPS * 2 * 2048);

    softmax_kernel<<<1, 64, 0, stream>>>(arch, norms, sw);
    build_w<<<(NEDGE * TAPS * 2 * 2048) / 256, 256, 0, stream>>>(
        w3, w5, w7, w1, s3dw, s3pw, s5dw, s5pw, d3, d5, sw, Wh);

    float* states[5] = {(float*)x, st1, st2, st3, out};
    int e = 0;
    for (int node = 0; node < 4; ++node) {
        int ebase = node * (node + 1) / 2;
        pool_node<<<(int)(S / 8 / 256), 256, 0, stream>>>(
            states[0], states[1], states[2], states[3],
            states[node + 1], sw, ebase, node + 1);
        for (int i = 0; i <= node; ++i) {
            conv_edge<<<NB * 4, 256, 0, stream>>>(states[i], states[node + 1], Wh, idx, sw, e);
            ++e;
        }
    }
}

// Round 5
// 1447.470 us; speedup vs baseline: 3.2352x; 1.3221x over previous
//
#include <hip/hip_runtime.h>
#include <math.h>

// LPCDARTS forward on MI355X — v7: occupancy-focused MFMA conv.
// Changes vs v6: (1) conv is one launch per NODE (blockIdx.y = edge),
// epilogue via atomicAdd so edges can run concurrently -> 2-3 blocks/CU on
// later nodes; (2) 512-thread blocks, 8 waves, one output row per wave ->
// 2+ waves/SIMD everywhere (was 1, OccupancyPercent 11%, MfmaUtil 9.6%).
// (Resubmission — round-4 bench failed with GPUAcquisitionTimeout before
//  any measurement.)

#define NB 64
#define CF 256
#define PC 64
#define HW 32
#define NEDGE 10
#define TAPS 81

// LDS tile geometry: 16 staged rows (8 output + 2*4 halo) x 40 cols x 32 ch
#define TR 16
#define TC 40
#define CSTR 40            // halves per pixel (32 ch + 8 pad) = 80 B
#define ROWSTR (TC * CSTR) // 1600 halves per row

typedef _Float16 f16x8 __attribute__((ext_vector_type(8)));
typedef _Float16 f16x2 __attribute__((ext_vector_type(2)));
typedef float f32x4 __attribute__((ext_vector_type(4)));

// ---------------- softmax over arch params (10 edges x 12 ops) -------------
__global__ void softmax_kernel(const float* __restrict__ arch,
                               const float* __restrict__ norms,
                               float* __restrict__ sw) {
    int e = threadIdx.x;
    if (e >= NEDGE) return;
    int node = 0, i = e;
    while (i > node) { i -= node + 1; node++; }
    float norm = fmaxf(norms[node * 5 + i], 1e-5f);
    const float* a = arch + (node * 5 + i) * 12;
    float v[12];
    float m = -3.0e38f;
    for (int k = 0; k < 12; ++k) { v[k] = a[k] / norm; m = fmaxf(m, v[k]); }
    float ssum = 0.f;
    for (int k = 0; k < 12; ++k) { v[k] = expf(v[k] - m); ssum += v[k]; }
    float inv = 1.0f / ssum;
    for (int k = 0; k < 12; ++k) sw[e * 12 + k] = v[k] * inv;
}

// ---------------- build combined 9x9 fp16 weights --------------------------
// Layout: Wh[e][tap][g][o][c32] halves (g = c>>5).  NO identity term (fp32
// epilogue handles w[0]).
__global__ void build_w(const float* __restrict__ w3, const float* __restrict__ w5,
                        const float* __restrict__ w7, const float* __restrict__ w1,
                        const float* __restrict__ s3dw, const float* __restrict__ s3pw,
                        const float* __restrict__ s5dw, const float* __restrict__ s5pw,
                        const float* __restrict__ d3, const float* __restrict__ d5,
                        const float* __restrict__ sw, _Float16* __restrict__ Wh) {
    int gid = blockIdx.x * 256 + threadIdx.x;  // 10*81*2*64*32 = 3,317,760
    int c32 = gid & 31;
    int o   = (gid >> 5) & 63;
    int g   = (gid >> 11) & 1;
    int t2  = gid >> 12;          // e*81 + tap
    int tap = t2 % TAPS;
    int e   = t2 / TAPS;
    int c   = (g << 5) | c32;

    int dy = tap / 9 - 4, dx = tap % 9 - 4;
    const float* w = sw + e * 12;
    int eoc = (e * 64 + o) * 64 + c;
    int ec  = e * 64 + c;
    float val = 0.f;
    int ady = dy < 0 ? -dy : dy, adx = dx < 0 ? -dx : dx;
    if (ady <= 1 && adx <= 1) {
        val += w[1] * w3[eoc * 9 + (dy + 1) * 3 + (dx + 1)];
        val += w[7] * s3pw[eoc] * s3dw[ec * 9 + (dy + 1) * 3 + (dx + 1)];
    }
    if (ady <= 2 && adx <= 2) {
        val += w[2] * w5[eoc * 25 + (dy + 2) * 5 + (dx + 2)];
        val += w[8] * s5pw[eoc] * s5dw[ec * 25 + (dy + 2) * 5 + (dx + 2)];
        if (((dy | dx) & 1) == 0)
            val += w[9] * d3[eoc * 9 + (dy / 2 + 1) * 3 + (dx / 2 + 1)];
    }
    if (ady <= 3 && adx <= 3)
        val += w[3] * w7[eoc * 49 + (dy + 3) * 7 + (dx + 3)];
    if (((dy | dx) & 1) == 0)
        val += w[10] * d5[eoc * 25 + (dy / 2 + 2) * 5 + (dx / 2 + 2)];
    if (dy == 0 && dx == 0)
        val += w[4] * w1[eoc];     // identity w[0] deliberately NOT added
    Wh[gid] = (_Float16)val;
}

// ---------------- pools (also zero-inits acc) ------------------------------
__global__ void pool_node(const float* __restrict__ s0, const float* __restrict__ s1,
                          const float* __restrict__ s2, const float* __restrict__ s3,
                          float* __restrict__ acc, const float* __restrict__ sw,
                          int ebase, int nedges) {
    int gid = blockIdx.x * 256 + threadIdx.x;  // over S/8 = 2,097,152
    int x0 = (gid & 3) << 3;                   // 0,8,16,24
    int y  = (gid >> 2) & 31;
    size_t plane = (size_t)(gid >> 7);         // (n, c)
    const float* states[4] = {s0, s1, s2, s3};
    float outv[8];
    #pragma unroll
    for (int j = 0; j < 8; ++j) outv[j] = 0.f;

    for (int i = 0; i < nedges; ++i) {
        const float* base = states[i] + (plane << 10);
        float colmax[10], colsum[10];
        #pragma unroll
        for (int j = 0; j < 10; ++j) { colmax[j] = -3.0e38f; colsum[j] = 0.f; }
        #pragma unroll
        for (int dr = -1; dr <= 1; ++dr) {
            int r = y + dr;
            if ((unsigned)r < 32u) {
                const float* rp = base + (r << 5);
                float vals[10];
                vals[0] = (x0 > 0) ? rp[x0 - 1] : 0.f;
                f32x4 m0 = *(const f32x4*)(rp + x0);
                f32x4 m1 = *(const f32x4*)(rp + x0 + 4);
                vals[1] = m0.x; vals[2] = m0.y; vals[3] = m0.z; vals[4] = m0.w;
                vals[5] = m1.x; vals[6] = m1.y; vals[7] = m1.z; vals[8] = m1.w;
                vals[9] = (x0 < 24) ? rp[x0 + 8] : 0.f;
                #pragma unroll
                for (int j = 0; j < 10; ++j) {
                    colsum[j] += vals[j];
                    colmax[j] = fmaxf(colmax[j], vals[j]);
                }
            }
        }
        if (x0 == 0)  colmax[0] = -3.0e38f;
        if (x0 == 24) colmax[9] = -3.0e38f;

        float wmax = sw[(ebase + i) * 12 + 5];
        float wavg = sw[(ebase + i) * 12 + 6] * (1.0f / 9.0f);
        #pragma unroll
        for (int j = 0; j < 8; ++j) {
            float mx = fmaxf(fmaxf(colmax[j], colmax[j + 1]), colmax[j + 2]);
            float sm = colsum[j] + colsum[j + 1] + colsum[j + 2];
            outv[j] += wmax * mx + wavg * sm;
        }
    }
    float* op = acc + (plane << 10) + (y << 5) + x0;
    ((f32x4*)op)[0] = (f32x4){outv[0], outv[1], outv[2], outv[3]};
    ((f32x4*)op)[1] = (f32x4){outv[4], outv[5], outv[6], outv[7]};
}

// ---------------- MFMA conv for all edges of one node ----------------------
// Grid: (64n x 4 strips, nedges).  Block: 512 thr = 8 waves.  Wave w owns
// output row y0+w (32 px) x 64 o = 8 C-frags (16x16x32 f16).  Epilogue uses
// atomicAdd since edges of a node run concurrently on the same acc.
__global__ __launch_bounds__(512, 2) void conv_node(
    const float* __restrict__ s0, const float* __restrict__ s1,
    const float* __restrict__ s2, const float* __restrict__ s3,
    float* __restrict__ acc, const _Float16* __restrict__ Wh,
    const int* __restrict__ idxg, const float* __restrict__ sw, int ebase) {
    __shared__ __align__(16) _Float16 tile[TR * ROWSTR];  // 51,200 B

    int i = blockIdx.y;
    int e = ebase + i;
    const float* sarr[4] = {s0, s1, s2, s3};
    const float* s = sarr[i];

    int t  = threadIdx.x;
    int qy = blockIdx.x & 3;
    int n  = blockIdx.x >> 2;
    int y0 = qy << 3;

    // zero whole tile once (interior rewritten per group; border stays 0)
    for (int l = t; l < TR * ROWSTR / 8; l += 512)
        ((f32x4*)tile)[l] = (f32x4){0.f, 0.f, 0.f, 0.f};

    int lane = t & 63;
    int wave = __builtin_amdgcn_readfirstlane(t >> 6);
    int aoff = ((lane & 15) << 5) + ((lane >> 4) << 3);   // halves into [o][c] 2048-chunk
    int boff = (lane & 15) * CSTR + ((lane >> 4) << 3);   // halves into tile row

    int sx = t & 31;        // staging x
    int cp = t >> 5;        // staging channel-pair slot 0..15

    f32x4 a[4][2];          // [o-frag][colblk]
    #pragma unroll
    for (int k = 0; k < 4; ++k) {
        a[k][0] = (f32x4){0.f, 0.f, 0.f, 0.f};
        a[k][1] = (f32x4){0.f, 0.f, 0.f, 0.f};
    }

    const int* ide = idxg + e * PC;

    __syncthreads();

    for (int g = 0; g < 2; ++g) {
        // ---- stage 32 gathered channels fp32->fp16 into [row][px][c] ----
        {
            int ca = (g << 5) + (cp << 1);
            const float* pa = s + (((size_t)n * CF + ide[ca]) << 10);
            const float* pb = s + (((size_t)n * CF + ide[ca + 1]) << 10);
            #pragma unroll
            for (int r = 0; r < TR; ++r) {
                int ys = y0 - 4 + r;
                if ((unsigned)ys < 32u) {
                    f16x2 h = {(_Float16)pa[(ys << 5) + sx], (_Float16)pb[(ys << 5) + sx]};
                    *(f16x2*)&tile[r * ROWSTR + (4 + sx) * CSTR + (cp << 1)] = h;
                }
            }
        }
        __syncthreads();

        const _Float16* wg = Wh + ((size_t)(e * TAPS) * 2 + g) * 2048 + aoff;
        for (int dy = 0; dy < 9; ++dy) {
            const _Float16* t0  = tile + (wave + dy) * ROWSTR + boff;
            const _Float16* wdy = wg + dy * 9 * 4096;
            #pragma unroll
            for (int dx = 0; dx < 9; ++dx) {
                const _Float16* wp = wdy + dx * 4096;
                f16x8 A0 = *(const f16x8*)(wp);
                f16x8 A1 = *(const f16x8*)(wp + 512);
                f16x8 A2 = *(const f16x8*)(wp + 1024);
                f16x8 A3 = *(const f16x8*)(wp + 1536);
                const _Float16* bp = t0 + dx * CSTR;
                f16x8 B0 = *(const f16x8*)(bp);
                f16x8 B1 = *(const f16x8*)(bp + 16 * CSTR);
                a[0][0] = __builtin_amdgcn_mfma_f32_16x16x32_f16(A0, B0, a[0][0], 0, 0, 0);
                a[0][1] = __builtin_amdgcn_mfma_f32_16x16x32_f16(A0, B1, a[0][1], 0, 0, 0);
                a[1][0] = __builtin_amdgcn_mfma_f32_16x16x32_f16(A1, B0, a[1][0], 0, 0, 0);
                a[1][1] = __builtin_amdgcn_mfma_f32_16x16x32_f16(A1, B1, a[1][1], 0, 0, 0);
                a[2][0] = __builtin_amdgcn_mfma_f32_16x16x32_f16(A2, B0, a[2][0], 0, 0, 0);
                a[2][1] = __builtin_amdgcn_mfma_f32_16x16x32_f16(A2, B1, a[2][1], 0, 0, 0);
                a[3][0] = __builtin_amdgcn_mfma_f32_16x16x32_f16(A3, B0, a[3][0], 0, 0, 0);
                a[3][1] = __builtin_amdgcn_mfma_f32_16x16x32_f16(A3, B1, a[3][1], 0, 0, 0);
            }
        }
        if (g == 0) __syncthreads();   // protect tile before group-1 restage
    }

    // ---- epilogue: atomic fp32 add into acc + fp32 identity term ----------
    // C/D layout: col = lane&15 (px), row = (lane>>4)*4 + reg (o within frag)
    float w0 = sw[e * 12];
    int y = y0 + wave;
    #pragma unroll
    for (int of = 0; of < 4; ++of) {
        #pragma unroll
        for (int j = 0; j < 4; ++j) {
            int o = (of << 4) + ((lane >> 4) << 2) + j;
            int ch = ide[o];
            size_t base = ((size_t)n * CF + ch) << 10;
            float* ap = acc + base;
            const float* sp = s + base;
            #pragma unroll
            for (int cb = 0; cb < 2; ++cb) {
                int off = (y << 5) + (cb << 4) + (lane & 15);
                atomicAdd(ap + off, a[of][cb][j] + w0 * sp[off]);
            }
        }
    }
}

extern "C" void kernel_launch(void* const* d_in, const int* in_sizes, int n_in,
                              void* d_out, int out_size, void* d_ws, size_t ws_size,
                              hipStream_t stream) {
    const float* x    = (const float*)d_in[0];
    const float* arch = (const float*)d_in[1];
    const float* norms= (const float*)d_in[2];
    const int*   idx  = (const int*)d_in[3];
    const float* w3   = (const float*)d_in[4];
    const float* w5   = (const float*)d_in[5];
    const float* w7   = (const float*)d_in[6];
    const float* w1   = (const float*)d_in[7];
    const float* s3dw = (const float*)d_in[8];
    const float* s3pw = (const float*)d_in[9];
    const float* s5dw = (const float*)d_in[10];
    const float* s5pw = (const float*)d_in[11];
    const float* d3   = (const float*)d_in[12];
    const float* d5   = (const float*)d_in[13];
    float* out = (float*)d_out;

    const size_t S = (size_t)NB * CF * HW * HW;  // 16,777,216 floats
    float* st1 = (float*)d_ws;
    float* st2 = st1 + S;
    float* st3 = st2 + S;
    _Float16* Wh = (_Float16*)(st3 + S);         // 10*81*2*64*32 halves = 6.64 MB
    float* sw = (float*)(Wh + (size_t)NEDGE * TAPS * 2 * 2048);

    softmax_kernel<<<1, 64, 0, stream>>>(arch, norms, sw);
    build_w<<<(NEDGE * TAPS * 2 * 2048) / 256, 256, 0, stream>>>(
        w3, w5, w7, w1, s3dw, s3pw, s5dw, s5pw, d3, d5, sw, Wh);

    float* states[5] = {(float*)x, st1, st2, st3, out};
    int e = 0;
    for (int node = 0; node < 4; ++node) {
        int ebase = node * (node + 1) / 2;
        pool_node<<<(int)(S / 8 / 256), 256, 0, stream>>>(
            states[0], states[1], states[2], states[3],
            states[node + 1], sw, ebase, node + 1);
        conv_node<<<dim3(NB * 4, node + 1), 512, 0, stream>>>(
            states[0], states[1], states[2], states[3],
            states[node + 1], Wh, idx, sw, ebase);
        e += node + 1;
    }
}

// Round 6
// 1114.779 us; speedup vs baseline: 4.2007x; 1.2984x over previous
//
#include <hip/hip_runtime.h>
#include <math.h>

// LPCDARTS forward on MI355X — v8: operand-bandwidth-focused MFMA conv.
// v7 post-mortem: MfmaUtil 18% with occupancy 46% -> waves are operand-starved
// (A 4KB + B 2KB per 39 MFMA cycles per wave).  v8: (1) wave = 2 rows x 64 o
// -> A-reuse 4, 16 MFMA/tap; (2) dx-outer/dy-inner with 2-entry B register
// ring -> fresh B ~2.2KB/tap (LDS demand under the 128 B/cyc port);
// (3) channel-group K-split via blockIdx.z (atomic epilogue) -> 256-thr
// blocks, 51.2KB LDS, 3 blocks/CU; identity term added by g==0 only.

#define NB 64
#define CF 256
#define PC 64
#define HW 32
#define NEDGE 10
#define TAPS 81

// LDS tile geometry: 16 staged rows (8 output + 2*4 halo) x 40 cols x 32 ch
#define TR 16
#define TC 40
#define CSTR 40            // halves per pixel (32 ch + 8 pad) = 80 B
#define ROWSTR (TC * CSTR) // 1600 halves per row

typedef _Float16 f16x8 __attribute__((ext_vector_type(8)));
typedef _Float16 f16x2 __attribute__((ext_vector_type(2)));
typedef float f32x4 __attribute__((ext_vector_type(4)));

// ---------------- softmax over arch params (10 edges x 12 ops) -------------
__global__ void softmax_kernel(const float* __restrict__ arch,
                               const float* __restrict__ norms,
                               float* __restrict__ sw) {
    int e = threadIdx.x;
    if (e >= NEDGE) return;
    int node = 0, i = e;
    while (i > node) { i -= node + 1; node++; }
    float norm = fmaxf(norms[node * 5 + i], 1e-5f);
    const float* a = arch + (node * 5 + i) * 12;
    float v[12];
    float m = -3.0e38f;
    for (int k = 0; k < 12; ++k) { v[k] = a[k] / norm; m = fmaxf(m, v[k]); }
    float ssum = 0.f;
    for (int k = 0; k < 12; ++k) { v[k] = expf(v[k] - m); ssum += v[k]; }
    float inv = 1.0f / ssum;
    for (int k = 0; k < 12; ++k) sw[e * 12 + k] = v[k] * inv;
}

// ---------------- build combined 9x9 fp16 weights --------------------------
// Layout: Wh[e][tap][g][o][c32] halves (g = c>>5).  NO identity term (fp32
// epilogue handles w[0]).
__global__ void build_w(const float* __restrict__ w3, const float* __restrict__ w5,
                        const float* __restrict__ w7, const float* __restrict__ w1,
                        const float* __restrict__ s3dw, const float* __restrict__ s3pw,
                        const float* __restrict__ s5dw, const float* __restrict__ s5pw,
                        const float* __restrict__ d3, const float* __restrict__ d5,
                        const float* __restrict__ sw, _Float16* __restrict__ Wh) {
    int gid = blockIdx.x * 256 + threadIdx.x;  // 10*81*2*64*32 = 3,317,760
    int c32 = gid & 31;
    int o   = (gid >> 5) & 63;
    int g   = (gid >> 11) & 1;
    int t2  = gid >> 12;          // e*81 + tap
    int tap = t2 % TAPS;
    int e   = t2 / TAPS;
    int c   = (g << 5) | c32;

    int dy = tap / 9 - 4, dx = tap % 9 - 4;
    const float* w = sw + e * 12;
    int eoc = (e * 64 + o) * 64 + c;
    int ec  = e * 64 + c;
    float val = 0.f;
    int ady = dy < 0 ? -dy : dy, adx = dx < 0 ? -dx : dx;
    if (ady <= 1 && adx <= 1) {
        val += w[1] * w3[eoc * 9 + (dy + 1) * 3 + (dx + 1)];
        val += w[7] * s3pw[eoc] * s3dw[ec * 9 + (dy + 1) * 3 + (dx + 1)];
    }
    if (ady <= 2 && adx <= 2) {
        val += w[2] * w5[eoc * 25 + (dy + 2) * 5 + (dx + 2)];
        val += w[8] * s5pw[eoc] * s5dw[ec * 25 + (dy + 2) * 5 + (dx + 2)];
        if (((dy | dx) & 1) == 0)
            val += w[9] * d3[eoc * 9 + (dy / 2 + 1) * 3 + (dx / 2 + 1)];
    }
    if (ady <= 3 && adx <= 3)
        val += w[3] * w7[eoc * 49 + (dy + 3) * 7 + (dx + 3)];
    if (((dy | dx) & 1) == 0)
        val += w[10] * d5[eoc * 25 + (dy / 2 + 2) * 5 + (dx / 2 + 2)];
    if (dy == 0 && dx == 0)
        val += w[4] * w1[eoc];     // identity w[0] deliberately NOT added
    Wh[gid] = (_Float16)val;
}

// ---------------- pools (also zero-inits acc) ------------------------------
__global__ void pool_node(const float* __restrict__ s0, const float* __restrict__ s1,
                          const float* __restrict__ s2, const float* __restrict__ s3,
                          float* __restrict__ acc, const float* __restrict__ sw,
                          int ebase, int nedges) {
    int gid = blockIdx.x * 256 + threadIdx.x;  // over S/8 = 2,097,152
    int x0 = (gid & 3) << 3;                   // 0,8,16,24
    int y  = (gid >> 2) & 31;
    size_t plane = (size_t)(gid >> 7);         // (n, c)
    const float* states[4] = {s0, s1, s2, s3};
    float outv[8];
    #pragma unroll
    for (int j = 0; j < 8; ++j) outv[j] = 0.f;

    for (int i = 0; i < nedges; ++i) {
        const float* base = states[i] + (plane << 10);
        float colmax[10], colsum[10];
        #pragma unroll
        for (int j = 0; j < 10; ++j) { colmax[j] = -3.0e38f; colsum[j] = 0.f; }
        #pragma unroll
        for (int dr = -1; dr <= 1; ++dr) {
            int r = y + dr;
            if ((unsigned)r < 32u) {
                const float* rp = base + (r << 5);
                float vals[10];
                vals[0] = (x0 > 0) ? rp[x0 - 1] : 0.f;
                f32x4 m0 = *(const f32x4*)(rp + x0);
                f32x4 m1 = *(const f32x4*)(rp + x0 + 4);
                vals[1] = m0.x; vals[2] = m0.y; vals[3] = m0.z; vals[4] = m0.w;
                vals[5] = m1.x; vals[6] = m1.y; vals[7] = m1.z; vals[8] = m1.w;
                vals[9] = (x0 < 24) ? rp[x0 + 8] : 0.f;
                #pragma unroll
                for (int j = 0; j < 10; ++j) {
                    colsum[j] += vals[j];
                    colmax[j] = fmaxf(colmax[j], vals[j]);
                }
            }
        }
        if (x0 == 0)  colmax[0] = -3.0e38f;
        if (x0 == 24) colmax[9] = -3.0e38f;

        float wmax = sw[(ebase + i) * 12 + 5];
        float wavg = sw[(ebase + i) * 12 + 6] * (1.0f / 9.0f);
        #pragma unroll
        for (int j = 0; j < 8; ++j) {
            float mx = fmaxf(fmaxf(colmax[j], colmax[j + 1]), colmax[j + 2]);
            float sm = colsum[j] + colsum[j + 1] + colsum[j + 2];
            outv[j] += wmax * mx + wavg * sm;
        }
    }
    float* op = acc + (plane << 10) + (y << 5) + x0;
    ((f32x4*)op)[0] = (f32x4){outv[0], outv[1], outv[2], outv[3]};
    ((f32x4*)op)[1] = (f32x4){outv[4], outv[5], outv[6], outv[7]};
}

// ---------------- MFMA conv for all edges of one node ----------------------
// Grid: (64n x 4 strips, nedges, 2 ch-groups).  Block: 256 thr = 4 waves.
// Wave w owns out rows y0+2w, y0+2w+1 (64 px) x 64 o = 16 C-frags.
// dx-outer / dy-inner with 2-entry B register ring (rows shared across dy).
// Epilogue: atomicAdd (edges + ch-groups run concurrently on the same acc).
__global__ __launch_bounds__(256, 3) void conv_node(
    const float* __restrict__ s0, const float* __restrict__ s1,
    const float* __restrict__ s2, const float* __restrict__ s3,
    float* __restrict__ acc, const _Float16* __restrict__ Wh,
    const int* __restrict__ idxg, const float* __restrict__ sw, int ebase) {
    __shared__ __align__(16) _Float16 tile[TR * ROWSTR];  // 51,200 B

    int i = blockIdx.y;
    int e = ebase + i;
    const float* sarr[4] = {s0, s1, s2, s3};
    const float* s = sarr[i];
    int g = blockIdx.z;

    int t  = threadIdx.x;
    int qy = blockIdx.x & 3;
    int n  = blockIdx.x >> 2;
    int y0 = qy << 3;

    // zero whole tile (interior rewritten by staging; border stays 0)
    for (int l = t; l < TR * ROWSTR / 8; l += 256)
        ((f32x4*)tile)[l] = (f32x4){0.f, 0.f, 0.f, 0.f};

    int lane = t & 63;
    int wave = __builtin_amdgcn_readfirstlane(t >> 6);
    int aoff = ((lane & 15) << 5) + ((lane >> 4) << 3);   // halves into [o][c32] chunk
    int boff = (lane & 15) * CSTR + ((lane >> 4) << 3);   // halves into tile row

    int sx = t & 31;        // staging x
    int cp = t >> 5;        // staging channel-pair slot 0..7

    f32x4 a[4][4];          // [o-frag][rs*2+cb]
    #pragma unroll
    for (int k = 0; k < 4; ++k)
        #pragma unroll
        for (int p = 0; p < 4; ++p) a[k][p] = (f32x4){0.f, 0.f, 0.f, 0.f};

    const int* ide = idxg + e * PC;

    __syncthreads();

    // ---- stage this block's 32-channel group fp32->fp16 into [row][px][c] -
    #pragma unroll
    for (int sub = 0; sub < 2; ++sub) {
        int c2 = cp + (sub << 3);                  // 0..15
        int ca = (g << 5) + (c2 << 1);
        const float* pa = s + (((size_t)n * CF + ide[ca]) << 10);
        const float* pb = s + (((size_t)n * CF + ide[ca + 1]) << 10);
        #pragma unroll
        for (int r = 0; r < TR; ++r) {
            int ys = y0 - 4 + r;
            if ((unsigned)ys < 32u) {
                f16x2 h = {(_Float16)pa[(ys << 5) + sx], (_Float16)pb[(ys << 5) + sx]};
                *(f16x2*)&tile[r * ROWSTR + (4 + sx) * CSTR + (c2 << 1)] = h;
            }
        }
    }
    __syncthreads();

    // ---- compute: dx outer, dy inner with B register ring -----------------
    const _Float16* wg = Wh + ((size_t)(e * TAPS) * 2 + g) * 2048 + aoff;
    int tb = wave << 1;     // tile row of wave's first output row
    for (int dx = 0; dx < 9; ++dx) {
        const _Float16* wx = wg + dx * 4096;
        const _Float16* brow = tile + boff + dx * CSTR;
        f16x8 F[2][2];      // ring: [parity][colblk]; indices constant after unroll
        F[0][0] = *(const f16x8*)(brow + tb * ROWSTR);
        F[0][1] = *(const f16x8*)(brow + tb * ROWSTR + 16 * CSTR);
        #pragma unroll
        for (int dy = 0; dy < 9; ++dy) {
            int rB = tb + dy + 1;
            F[(dy + 1) & 1][0] = *(const f16x8*)(brow + rB * ROWSTR);
            F[(dy + 1) & 1][1] = *(const f16x8*)(brow + rB * ROWSTR + 16 * CSTR);
            const _Float16* wp = wx + dy * 9 * 4096;
            f16x8 A0 = *(const f16x8*)(wp);
            f16x8 A1 = *(const f16x8*)(wp + 512);
            f16x8 A2 = *(const f16x8*)(wp + 1024);
            f16x8 A3 = *(const f16x8*)(wp + 1536);
            // row A (already-resident ring entry) first, fresh row B last
            a[0][0] = __builtin_amdgcn_mfma_f32_16x16x32_f16(A0, F[dy & 1][0], a[0][0], 0, 0, 0);
            a[1][0] = __builtin_amdgcn_mfma_f32_16x16x32_f16(A1, F[dy & 1][0], a[1][0], 0, 0, 0);
            a[2][0] = __builtin_amdgcn_mfma_f32_16x16x32_f16(A2, F[dy & 1][0], a[2][0], 0, 0, 0);
            a[3][0] = __builtin_amdgcn_mfma_f32_16x16x32_f16(A3, F[dy & 1][0], a[3][0], 0, 0, 0);
            a[0][1] = __builtin_amdgcn_mfma_f32_16x16x32_f16(A0, F[dy & 1][1], a[0][1], 0, 0, 0);
            a[1][1] = __builtin_amdgcn_mfma_f32_16x16x32_f16(A1, F[dy & 1][1], a[1][1], 0, 0, 0);
            a[2][1] = __builtin_amdgcn_mfma_f32_16x16x32_f16(A2, F[dy & 1][1], a[2][1], 0, 0, 0);
            a[3][1] = __builtin_amdgcn_mfma_f32_16x16x32_f16(A3, F[dy & 1][1], a[3][1], 0, 0, 0);
            a[0][2] = __builtin_amdgcn_mfma_f32_16x16x32_f16(A0, F[(dy + 1) & 1][0], a[0][2], 0, 0, 0);
            a[1][2] = __builtin_amdgcn_mfma_f32_16x16x32_f16(A1, F[(dy + 1) & 1][0], a[1][2], 0, 0, 0);
            a[2][2] = __builtin_amdgcn_mfma_f32_16x16x32_f16(A2, F[(dy + 1) & 1][0], a[2][2], 0, 0, 0);
            a[3][2] = __builtin_amdgcn_mfma_f32_16x16x32_f16(A3, F[(dy + 1) & 1][0], a[3][2], 0, 0, 0);
            a[0][3] = __builtin_amdgcn_mfma_f32_16x16x32_f16(A0, F[(dy + 1) & 1][1], a[0][3], 0, 0, 0);
            a[1][3] = __builtin_amdgcn_mfma_f32_16x16x32_f16(A1, F[(dy + 1) & 1][1], a[1][3], 0, 0, 0);
            a[2][3] = __builtin_amdgcn_mfma_f32_16x16x32_f16(A2, F[(dy + 1) & 1][1], a[2][3], 0, 0, 0);
            a[3][3] = __builtin_amdgcn_mfma_f32_16x16x32_f16(A3, F[(dy + 1) & 1][1], a[3][3], 0, 0, 0);
        }
    }

    // ---- epilogue: atomic fp32 add into acc (+ identity, g==0 only) -------
    // C/D layout: col = lane&15 (px), row = (lane>>4)*4 + reg (o within frag)
    if (g == 0) {
        float w0 = sw[e * 12];
        #pragma unroll
        for (int of = 0; of < 4; ++of) {
            #pragma unroll
            for (int j = 0; j < 4; ++j) {
                int o = (of << 4) + ((lane >> 4) << 2) + j;
                int ch = ide[o];
                size_t base = ((size_t)n * CF + ch) << 10;
                float* ap = acc + base;
                const float* sp = s + base;
                #pragma unroll
                for (int rs = 0; rs < 2; ++rs) {
                    int y = y0 + (wave << 1) + rs;
                    #pragma unroll
                    for (int cb = 0; cb < 2; ++cb) {
                        int off = (y << 5) + (cb << 4) + (lane & 15);
                        atomicAdd(ap + off, a[of][(rs << 1) + cb][j] + w0 * sp[off]);
                    }
                }
            }
        }
    } else {
        #pragma unroll
        for (int of = 0; of < 4; ++of) {
            #pragma unroll
            for (int j = 0; j < 4; ++j) {
                int o = (of << 4) + ((lane >> 4) << 2) + j;
                int ch = ide[o];
                float* ap = acc + (((size_t)n * CF + ch) << 10);
                #pragma unroll
                for (int rs = 0; rs < 2; ++rs) {
                    int y = y0 + (wave << 1) + rs;
                    #pragma unroll
                    for (int cb = 0; cb < 2; ++cb) {
                        int off = (y << 5) + (cb << 4) + (lane & 15);
                        atomicAdd(ap + off, a[of][(rs << 1) + cb][j]);
                    }
                }
            }
        }
    }
}

extern "C" void kernel_launch(void* const* d_in, const int* in_sizes, int n_in,
                              void* d_out, int out_size, void* d_ws, size_t ws_size,
                              hipStream_t stream) {
    const float* x    = (const float*)d_in[0];
    const float* arch = (const float*)d_in[1];
    const float* norms= (const float*)d_in[2];
    const int*   idx  = (const int*)d_in[3];
    const float* w3   = (const float*)d_in[4];
    const float* w5   = (const float*)d_in[5];
    const float* w7   = (const float*)d_in[6];
    const float* w1   = (const float*)d_in[7];
    const float* s3dw = (const float*)d_in[8];
    const float* s3pw = (const float*)d_in[9];
    const float* s5dw = (const float*)d_in[10];
    const float* s5pw = (const float*)d_in[11];
    const float* d3   = (const float*)d_in[12];
    const float* d5   = (const float*)d_in[13];
    float* out = (float*)d_out;

    const size_t S = (size_t)NB * CF * HW * HW;  // 16,777,216 floats
    float* st1 = (float*)d_ws;
    float* st2 = st1 + S;
    float* st3 = st2 + S;
    _Float16* Wh = (_Float16*)(st3 + S);         // 10*81*2*64*32 halves = 6.64 MB
    float* sw = (float*)(Wh + (size_t)NEDGE * TAPS * 2 * 2048);

    softmax_kernel<<<1, 64, 0, stream>>>(arch, norms, sw);
    build_w<<<(NEDGE * TAPS * 2 * 2048) / 256, 256, 0, stream>>>(
        w3, w5, w7, w1, s3dw, s3pw, s5dw, s5pw, d3, d5, sw, Wh);

    float* states[5] = {(float*)x, st1, st2, st3, out};
    for (int node = 0; node < 4; ++node) {
        int ebase = node * (node + 1) / 2;
        pool_node<<<(int)(S / 8 / 256), 256, 0, stream>>>(
            states[0], states[1], states[2], states[3],
            states[node + 1], sw, ebase, node + 1);
        conv_node<<<dim3(NB * 4, node + 1, 2), 256, 0, stream>>>(
            states[0], states[1], states[2], states[3],
            states[node + 1], Wh, idx, sw, ebase);
    }
}

// Round 7
// 1106.992 us; speedup vs baseline: 4.2302x; 1.0070x over previous
//
#include <hip/hip_runtime.h>
#include <math.h>

// LPCDARTS forward on MI355X — v9: software-pipelined A-fragment stream.
// v8 post-mortem: MfmaUtil 24.5% / VALUBusy 8.6% / HBM 9.4% -> latency-bound:
// per-iter A (weight) loads are consumed immediately; ~200-900cy latency vs
// 256cy MFMA burst, 3 waves/SIMD can't hide it.  v9 flattens the 81-tap loop
// (full unroll), double-buffers A in registers, and issues tap t+1's loads
// before tap t's MFMAs -> load->use distance = 1 full iteration.

#define NB 64
#define CF 256
#define PC 64
#define HW 32
#define NEDGE 10
#define TAPS 81

// LDS tile geometry: 16 staged rows (8 output + 2*4 halo) x 40 cols x 32 ch
#define TR 16
#define TC 40
#define CSTR 40            // halves per pixel (32 ch + 8 pad) = 80 B
#define ROWSTR (TC * CSTR) // 1600 halves per row

typedef _Float16 f16x8 __attribute__((ext_vector_type(8)));
typedef _Float16 f16x2 __attribute__((ext_vector_type(2)));
typedef float f32x4 __attribute__((ext_vector_type(4)));

// ---------------- softmax over arch params (10 edges x 12 ops) -------------
__global__ void softmax_kernel(const float* __restrict__ arch,
                               const float* __restrict__ norms,
                               float* __restrict__ sw) {
    int e = threadIdx.x;
    if (e >= NEDGE) return;
    int node = 0, i = e;
    while (i > node) { i -= node + 1; node++; }
    float norm = fmaxf(norms[node * 5 + i], 1e-5f);
    const float* a = arch + (node * 5 + i) * 12;
    float v[12];
    float m = -3.0e38f;
    for (int k = 0; k < 12; ++k) { v[k] = a[k] / norm; m = fmaxf(m, v[k]); }
    float ssum = 0.f;
    for (int k = 0; k < 12; ++k) { v[k] = expf(v[k] - m); ssum += v[k]; }
    float inv = 1.0f / ssum;
    for (int k = 0; k < 12; ++k) sw[e * 12 + k] = v[k] * inv;
}

// ---------------- build combined 9x9 fp16 weights --------------------------
// Layout: Wh[e][tap][g][o][c32] halves (g = c>>5).  NO identity term (fp32
// epilogue handles w[0]).
__global__ void build_w(const float* __restrict__ w3, const float* __restrict__ w5,
                        const float* __restrict__ w7, const float* __restrict__ w1,
                        const float* __restrict__ s3dw, const float* __restrict__ s3pw,
                        const float* __restrict__ s5dw, const float* __restrict__ s5pw,
                        const float* __restrict__ d3, const float* __restrict__ d5,
                        const float* __restrict__ sw, _Float16* __restrict__ Wh) {
    int gid = blockIdx.x * 256 + threadIdx.x;  // 10*81*2*64*32 = 3,317,760
    int c32 = gid & 31;
    int o   = (gid >> 5) & 63;
    int g   = (gid >> 11) & 1;
    int t2  = gid >> 12;          // e*81 + tap
    int tap = t2 % TAPS;
    int e   = t2 / TAPS;
    int c   = (g << 5) | c32;

    int dy = tap / 9 - 4, dx = tap % 9 - 4;
    const float* w = sw + e * 12;
    int eoc = (e * 64 + o) * 64 + c;
    int ec  = e * 64 + c;
    float val = 0.f;
    int ady = dy < 0 ? -dy : dy, adx = dx < 0 ? -dx : dx;
    if (ady <= 1 && adx <= 1) {
        val += w[1] * w3[eoc * 9 + (dy + 1) * 3 + (dx + 1)];
        val += w[7] * s3pw[eoc] * s3dw[ec * 9 + (dy + 1) * 3 + (dx + 1)];
    }
    if (ady <= 2 && adx <= 2) {
        val += w[2] * w5[eoc * 25 + (dy + 2) * 5 + (dx + 2)];
        val += w[8] * s5pw[eoc] * s5dw[ec * 25 + (dy + 2) * 5 + (dx + 2)];
        if (((dy | dx) & 1) == 0)
            val += w[9] * d3[eoc * 9 + (dy / 2 + 1) * 3 + (dx / 2 + 1)];
    }
    if (ady <= 3 && adx <= 3)
        val += w[3] * w7[eoc * 49 + (dy + 3) * 7 + (dx + 3)];
    if (((dy | dx) & 1) == 0)
        val += w[10] * d5[eoc * 25 + (dy / 2 + 2) * 5 + (dx / 2 + 2)];
    if (dy == 0 && dx == 0)
        val += w[4] * w1[eoc];     // identity w[0] deliberately NOT added
    Wh[gid] = (_Float16)val;
}

// ---------------- pools (also zero-inits acc) ------------------------------
__global__ void pool_node(const float* __restrict__ s0, const float* __restrict__ s1,
                          const float* __restrict__ s2, const float* __restrict__ s3,
                          float* __restrict__ acc, const float* __restrict__ sw,
                          int ebase, int nedges) {
    int gid = blockIdx.x * 256 + threadIdx.x;  // over S/8 = 2,097,152
    int x0 = (gid & 3) << 3;                   // 0,8,16,24
    int y  = (gid >> 2) & 31;
    size_t plane = (size_t)(gid >> 7);         // (n, c)
    const float* states[4] = {s0, s1, s2, s3};
    float outv[8];
    #pragma unroll
    for (int j = 0; j < 8; ++j) outv[j] = 0.f;

    for (int i = 0; i < nedges; ++i) {
        const float* base = states[i] + (plane << 10);
        float colmax[10], colsum[10];
        #pragma unroll
        for (int j = 0; j < 10; ++j) { colmax[j] = -3.0e38f; colsum[j] = 0.f; }
        #pragma unroll
        for (int dr = -1; dr <= 1; ++dr) {
            int r = y + dr;
            if ((unsigned)r < 32u) {
                const float* rp = base + (r << 5);
                float vals[10];
                vals[0] = (x0 > 0) ? rp[x0 - 1] : 0.f;
                f32x4 m0 = *(const f32x4*)(rp + x0);
                f32x4 m1 = *(const f32x4*)(rp + x0 + 4);
                vals[1] = m0.x; vals[2] = m0.y; vals[3] = m0.z; vals[4] = m0.w;
                vals[5] = m1.x; vals[6] = m1.y; vals[7] = m1.z; vals[8] = m1.w;
                vals[9] = (x0 < 24) ? rp[x0 + 8] : 0.f;
                #pragma unroll
                for (int j = 0; j < 10; ++j) {
                    colsum[j] += vals[j];
                    colmax[j] = fmaxf(colmax[j], vals[j]);
                }
            }
        }
        if (x0 == 0)  colmax[0] = -3.0e38f;
        if (x0 == 24) colmax[9] = -3.0e38f;

        float wmax = sw[(ebase + i) * 12 + 5];
        float wavg = sw[(ebase + i) * 12 + 6] * (1.0f / 9.0f);
        #pragma unroll
        for (int j = 0; j < 8; ++j) {
            float mx = fmaxf(fmaxf(colmax[j], colmax[j + 1]), colmax[j + 2]);
            float sm = colsum[j] + colsum[j + 1] + colsum[j + 2];
            outv[j] += wmax * mx + wavg * sm;
        }
    }
    float* op = acc + (plane << 10) + (y << 5) + x0;
    ((f32x4*)op)[0] = (f32x4){outv[0], outv[1], outv[2], outv[3]};
    ((f32x4*)op)[1] = (f32x4){outv[4], outv[5], outv[6], outv[7]};
}

// ---------------- MFMA conv for all edges of one node ----------------------
// Grid: (64n x 4 strips, nedges, 2 ch-groups).  Block: 256 thr = 4 waves.
// Wave w owns out rows y0+2w, y0+2w+1 (64 px) x 64 o = 16 C-frags.
// Flat 81-tap loop (full unroll), A double-buffered with 1-iter prefetch,
// B 2-entry register ring (rows shared across y-shift).
// Epilogue: atomicAdd (edges + ch-groups run concurrently on the same acc).
__global__ __launch_bounds__(256, 3) void conv_node(
    const float* __restrict__ s0, const float* __restrict__ s1,
    const float* __restrict__ s2, const float* __restrict__ s3,
    float* __restrict__ acc, const _Float16* __restrict__ Wh,
    const int* __restrict__ idxg, const float* __restrict__ sw, int ebase) {
    __shared__ __align__(16) _Float16 tile[TR * ROWSTR];  // 51,200 B

    int i = blockIdx.y;
    int e = ebase + i;
    const float* sarr[4] = {s0, s1, s2, s3};
    const float* s = sarr[i];
    int g = blockIdx.z;

    int t  = threadIdx.x;
    int qy = blockIdx.x & 3;
    int n  = blockIdx.x >> 2;
    int y0 = qy << 3;

    // zero whole tile (interior rewritten by staging; border stays 0)
    for (int l = t; l < TR * ROWSTR / 8; l += 256)
        ((f32x4*)tile)[l] = (f32x4){0.f, 0.f, 0.f, 0.f};

    int lane = t & 63;
    int wave = __builtin_amdgcn_readfirstlane(t >> 6);
    int aoff = ((lane & 15) << 5) + ((lane >> 4) << 3);   // halves into [o][c32] chunk
    int boff = (lane & 15) * CSTR + ((lane >> 4) << 3);   // halves into tile row

    int sx = t & 31;        // staging x
    int cp = t >> 5;        // staging channel-pair slot 0..7

    f32x4 a[4][4];          // [o-frag][rs*2+cb]
    #pragma unroll
    for (int k = 0; k < 4; ++k)
        #pragma unroll
        for (int p = 0; p < 4; ++p) a[k][p] = (f32x4){0.f, 0.f, 0.f, 0.f};

    const int* ide = idxg + e * PC;

    __syncthreads();

    // ---- stage this block's 32-channel group fp32->fp16 into [row][px][c] -
    #pragma unroll
    for (int sub = 0; sub < 2; ++sub) {
        int c2 = cp + (sub << 3);                  // 0..15
        int ca = (g << 5) + (c2 << 1);
        const float* pa = s + (((size_t)n * CF + ide[ca]) << 10);
        const float* pb = s + (((size_t)n * CF + ide[ca + 1]) << 10);
        #pragma unroll
        for (int r = 0; r < TR; ++r) {
            int ys = y0 - 4 + r;
            if ((unsigned)ys < 32u) {
                f16x2 h = {(_Float16)pa[(ys << 5) + sx], (_Float16)pb[(ys << 5) + sx]};
                *(f16x2*)&tile[r * ROWSTR + (4 + sx) * CSTR + (c2 << 1)] = h;
            }
        }
    }
    __syncthreads();

    // ---- compute: flat tap loop, x-shift outer / y-shift inner ------------
    // Weight addr for (dx outer, dy inner): wg + (dy*9 + dx)*4096 halves.
    const _Float16* wg = Wh + ((size_t)(e * TAPS) * 2 + g) * 2048 + aoff;
    const _Float16* bt = tile + boff;
    int tb = wave << 1;     // tile row of wave's first output row

    f16x8 A2b[2][4];        // A double buffer; indices compile-time (full unroll)
    f16x8 F[2][2];          // B ring: [parity][colblk]
    // prime A for tap 0 (dx=0, dy=0)
    #pragma unroll
    for (int k = 0; k < 4; ++k) A2b[0][k] = *(const f16x8*)(wg + 512 * k);

    #pragma unroll
    for (int tp = 0; tp < 81; ++tp) {
        const int dx = tp / 9, dy = tp % 9;
        // 1) prefetch A for tap tp+1 (issued ~1 full iteration before use)
        if (tp + 1 < 81) {
            const int ntp = tp + 1;
            const int ndx = ntp / 9, ndy = ntp % 9;
            const _Float16* wp = wg + (ndy * 9 + ndx) * 4096;
            #pragma unroll
            for (int k = 0; k < 4; ++k) A2b[(tp + 1) & 1][k] = *(const f16x8*)(wp + 512 * k);
        }
        // 2) B ring maintenance (LDS reads)
        const _Float16* brow = bt + dx * CSTR;
        if (dy == 0) {      // new x-shift column: base row
            F[0][0] = *(const f16x8*)(brow + tb * ROWSTR);
            F[0][1] = *(const f16x8*)(brow + tb * ROWSTR + 16 * CSTR);
        }
        {
            const int rB = tb + dy + 1;
            F[(dy + 1) & 1][0] = *(const f16x8*)(brow + rB * ROWSTR);
            F[(dy + 1) & 1][1] = *(const f16x8*)(brow + rB * ROWSTR + 16 * CSTR);
        }
        // 3) 16 MFMAs; resident ring entry first, fresh row last
        a[0][0] = __builtin_amdgcn_mfma_f32_16x16x32_f16(A2b[tp & 1][0], F[dy & 1][0], a[0][0], 0, 0, 0);
        a[1][0] = __builtin_amdgcn_mfma_f32_16x16x32_f16(A2b[tp & 1][1], F[dy & 1][0], a[1][0], 0, 0, 0);
        a[2][0] = __builtin_amdgcn_mfma_f32_16x16x32_f16(A2b[tp & 1][2], F[dy & 1][0], a[2][0], 0, 0, 0);
        a[3][0] = __builtin_amdgcn_mfma_f32_16x16x32_f16(A2b[tp & 1][3], F[dy & 1][0], a[3][0], 0, 0, 0);
        a[0][1] = __builtin_amdgcn_mfma_f32_16x16x32_f16(A2b[tp & 1][0], F[dy & 1][1], a[0][1], 0, 0, 0);
        a[1][1] = __builtin_amdgcn_mfma_f32_16x16x32_f16(A2b[tp & 1][1], F[dy & 1][1], a[1][1], 0, 0, 0);
        a[2][1] = __builtin_amdgcn_mfma_f32_16x16x32_f16(A2b[tp & 1][2], F[dy & 1][1], a[2][1], 0, 0, 0);
        a[3][1] = __builtin_amdgcn_mfma_f32_16x16x32_f16(A2b[tp & 1][3], F[dy & 1][1], a[3][1], 0, 0, 0);
        a[0][2] = __builtin_amdgcn_mfma_f32_16x16x32_f16(A2b[tp & 1][0], F[(dy + 1) & 1][0], a[0][2], 0, 0, 0);
        a[1][2] = __builtin_amdgcn_mfma_f32_16x16x32_f16(A2b[tp & 1][1], F[(dy + 1) & 1][0], a[1][2], 0, 0, 0);
        a[2][2] = __builtin_amdgcn_mfma_f32_16x16x32_f16(A2b[tp & 1][2], F[(dy + 1) & 1][0], a[2][2], 0, 0, 0);
        a[3][2] = __builtin_amdgcn_mfma_f32_16x16x32_f16(A2b[tp & 1][3], F[(dy + 1) & 1][0], a[3][2], 0, 0, 0);
        a[0][3] = __builtin_amdgcn_mfma_f32_16x16x32_f16(A2b[tp & 1][0], F[(dy + 1) & 1][1], a[0][3], 0, 0, 0);
        a[1][3] = __builtin_amdgcn_mfma_f32_16x16x32_f16(A2b[tp & 1][1], F[(dy + 1) & 1][1], a[1][3], 0, 0, 0);
        a[2][3] = __builtin_amdgcn_mfma_f32_16x16x32_f16(A2b[tp & 1][2], F[(dy + 1) & 1][1], a[2][3], 0, 0, 0);
        a[3][3] = __builtin_amdgcn_mfma_f32_16x16x32_f16(A2b[tp & 1][3], F[(dy + 1) & 1][1], a[3][3], 0, 0, 0);
    }

    // ---- epilogue: atomic fp32 add into acc (+ identity, g==0 only) -------
    // C/D layout: col = lane&15 (px), row = (lane>>4)*4 + reg (o within frag)
    if (g == 0) {
        float w0 = sw[e * 12];
        #pragma unroll
        for (int of = 0; of < 4; ++of) {
            #pragma unroll
            for (int j = 0; j < 4; ++j) {
                int o = (of << 4) + ((lane >> 4) << 2) + j;
                int ch = ide[o];
                size_t base = ((size_t)n * CF + ch) << 10;
                float* ap = acc + base;
                const float* sp = s + base;
                #pragma unroll
                for (int rs = 0; rs < 2; ++rs) {
                    int y = y0 + (wave << 1) + rs;
                    #pragma unroll
                    for (int cb = 0; cb < 2; ++cb) {
                        int off = (y << 5) + (cb << 4) + (lane & 15);
                        atomicAdd(ap + off, a[of][(rs << 1) + cb][j] + w0 * sp[off]);
                    }
                }
            }
        }
    } else {
        #pragma unroll
        for (int of = 0; of < 4; ++of) {
            #pragma unroll
            for (int j = 0; j < 4; ++j) {
                int o = (of << 4) + ((lane >> 4) << 2) + j;
                int ch = ide[o];
                float* ap = acc + (((size_t)n * CF + ch) << 10);
                #pragma unroll
                for (int rs = 0; rs < 2; ++rs) {
                    int y = y0 + (wave << 1) + rs;
                    #pragma unroll
                    for (int cb = 0; cb < 2; ++cb) {
                        int off = (y << 5) + (cb << 4) + (lane & 15);
                        atomicAdd(ap + off, a[of][(rs << 1) + cb][j]);
                    }
                }
            }
        }
    }
}

extern "C" void kernel_launch(void* const* d_in, const int* in_sizes, int n_in,
                              void* d_out, int out_size, void* d_ws, size_t ws_size,
                              hipStream_t stream) {
    const float* x    = (const float*)d_in[0];
    const float* arch = (const float*)d_in[1];
    const float* norms= (const float*)d_in[2];
    const int*   idx  = (const int*)d_in[3];
    const float* w3   = (const float*)d_in[4];
    const float* w5   = (const float*)d_in[5];
    const float* w7   = (const float*)d_in[6];
    const float* w1   = (const float*)d_in[7];
    const float* s3dw = (const float*)d_in[8];
    const float* s3pw = (const float*)d_in[9];
    const float* s5dw = (const float*)d_in[10];
    const float* s5pw = (const float*)d_in[11];
    const float* d3   = (const float*)d_in[12];
    const float* d5   = (const float*)d_in[13];
    float* out = (float*)d_out;

    const size_t S = (size_t)NB * CF * HW * HW;  // 16,777,216 floats
    float* st1 = (float*)d_ws;
    float* st2 = st1 + S;
    float* st3 = st2 + S;
    _Float16* Wh = (_Float16*)(st3 + S);         // 10*81*2*64*32 halves = 6.64 MB
    float* sw = (float*)(Wh + (size_t)NEDGE * TAPS * 2 * 2048);

    softmax_kernel<<<1, 64, 0, stream>>>(arch, norms, sw);
    build_w<<<(NEDGE * TAPS * 2 * 2048) / 256, 256, 0, stream>>>(
        w3, w5, w7, w1, s3dw, s3pw, s5dw, s5pw, d3, d5, sw, Wh);

    float* states[5] = {(float*)x, st1, st2, st3, out};
    for (int node = 0; node < 4; ++node) {
        int ebase = node * (node + 1) / 2;
        pool_node<<<(int)(S / 8 / 256), 256, 0, stream>>>(
            states[0], states[1], states[2], states[3],
            states[node + 1], sw, ebase, node + 1);
        conv_node<<<dim3(NB * 4, node + 1, 2), 256, 0, stream>>>(
            states[0], states[1], states[2], states[3],
            states[node + 1], Wh, idx, sw, ebase);
    }
}